// Round 7
// baseline (152.954 us; speedup 1.0000x reference)
//
#include <hip/hip_runtime.h>
#include <stdint.h>

#define D 1024
#define KOUT 128
#define BM 128
#define NSTEPS 64

typedef __attribute__((ext_vector_type(8))) __bf16 bf16x8;
typedef __attribute__((ext_vector_type(4))) float f32x4;

// DPP row_ror add: v += rotate_within_16(v, N). Rows of 16 consecutive lanes.
template <int CTRL>
__device__ __forceinline__ float dpp_ror_add(float v) {
    int t = __builtin_amdgcn_update_dpp(
        0, __builtin_bit_cast(int, v), CTRL, 0xf, 0xf, true);
    return v + __builtin_bit_cast(float, t);
}

// ---------------- diag: dvec[i] = b[i] + (1/(d*B)) * sum_j W[i,j]*colsum[j] ----
__global__ __launch_bounds__(256) void diag_kernel(
    const float* __restrict__ W, const float* __restrict__ bias,
    const float* __restrict__ colsum, float* __restrict__ dvec, float inv_scale) {
    int i = blockIdx.x;
    int tid = threadIdx.x;
    float s = 0.f;
    for (int j = tid; j < D; j += 256) s += W[i * D + j] * colsum[j];
    #pragma unroll
    for (int off = 32; off > 0; off >>= 1) s += __shfl_down(s, off, 64);
    __shared__ float wsum[4];
    if ((tid & 63) == 0) wsum[tid >> 6] = s;
    __syncthreads();
    if (tid == 0)
        dvec[i] = bias[i] + (wsum[0] + wsum[1] + wsum[2] + wsum[3]) * inv_scale;
}

// ---------------- vconv: staging-ready, pre-swizzled hi/lo split of V ----------
__global__ __launch_bounds__(256) void vconv_kernel(
    const float* __restrict__ V, char* __restrict__ Vstage) {
    int idx = blockIdx.x * 256 + threadIdx.x;   // over 2048*128 elements of V[k][n]
    int k = idx >> 7;
    int n = idx & 127;
    float x = V[idx];
    __bf16 h = (__bf16)x;
    __bf16 l = (__bf16)(x - (float)h);
    int kstep = k >> 5;
    int kk = k & 31;
    uint32_t sw = ((uint32_t)(n & 7)) << 4;
    uint32_t oh = (uint32_t)(n * 128 + kk * 2);
    char* base = Vstage + (size_t)kstep * 16384;
    *(__bf16*)(base + (oh ^ sw)) = h;
    *(__bf16*)(base + ((oh + 64) ^ sw)) = l;
}

// ---------------- fused GEMM + colsum --------------------------------------
// Tile: BM=128 x 128 cols, BK=32. 4 waves in 2x2: rowhalf=wave&1 (64 rows),
// colhalf=wave>>1 (64 cols); per wave rt=4 x ct=4 -> 48 MFMA / 16 ds_read_b128.
// K-step order: s even -> e1 cols [t*32..), s odd -> e2 same cols (t=s>>1).
// A and B each 4-buffered; per-iter issue {B(s+3), A(s+3)}; end-iter
// s_waitcnt vmcnt(16) completes B(s+1)+A(s+1), leaves 16 loads (64KB) in
// flight; raw s_barrier (no drain). Fused colsum on waves 0,1 only.
__global__ __launch_bounds__(256, 1) void mfma_gemm_fused(
    const float* __restrict__ e1, const float* __restrict__ e2,
    const char* __restrict__ Vstage, float* __restrict__ ff,
    float* __restrict__ colsum) {
    __shared__ char As[4][16384];
    __shared__ char Bs[4][16384];
    __shared__ float cs[1024];

    int tid  = threadIdx.x;
    int wave = tid >> 6;
    int lane = tid & 63;
    int lrow = lane & 15;
    int lk   = lane >> 4;                  // 0..3
    int rowhalf = wave & 1;
    int colhalf = wave >> 1;
    long m0  = (long)blockIdx.x * BM;

    for (int i = tid; i < 1024; i += 256) cs[i] = 0.f;

    f32x4 acc[4][4];
    #pragma unroll
    for (int rt = 0; rt < 4; ++rt)
        #pragma unroll
        for (int ct = 0; ct < 4; ++ct) acc[rt][ct] = (f32x4){0.f, 0.f, 0.f, 0.f};

    auto stage_A = [&](int s, int buf) {
        int ss = s & 63;
        const float* src = (ss & 1) ? e2 : e1;
        int kcb = (ss >> 1) << 7;          // byte col offset = t*32 floats
        #pragma unroll
        for (int r = 0; r < 4; ++r) {
            uint32_t slot = (uint32_t)(r * 4096 + tid * 16);
            uint32_t row  = slot >> 7;     // 0..127
            uint32_t o    = slot ^ ((row & 7u) << 4);
            const char* g = (const char*)src + (((long)(m0 + row)) << 12)
                            + kcb + (o & 127u);
            char* l = &As[buf][r * 4096 + wave * 1024];
            __builtin_amdgcn_global_load_lds(
                (const __attribute__((address_space(1))) uint32_t*)g,
                (__attribute__((address_space(3))) uint32_t*)l, 16, 0, 0);
        }
    };
    auto stage_B = [&](int s, int buf) {
        int ss = s & 63;
        int bt = ((ss & 1) << 5) + (ss >> 1);
        const char* gb = Vstage + (size_t)bt * 16384;
        #pragma unroll
        for (int r = 0; r < 4; ++r) {
            const char* g = gb + r * 4096 + tid * 16;
            char* l = &Bs[buf][r * 4096 + wave * 1024];
            __builtin_amdgcn_global_load_lds(
                (const __attribute__((address_space(1))) uint32_t*)g,
                (__attribute__((address_space(3))) uint32_t*)l, 16, 0, 0);
        }
    };

    // prologue: FIFO = B0,A0,B1,A1,B2,A2 (24 loads); vmcnt(16) -> B0,A0 done
    stage_B(0, 0); stage_A(0, 0);
    stage_B(1, 1); stage_A(1, 1);
    stage_B(2, 2); stage_A(2, 2);
    asm volatile("s_waitcnt vmcnt(16)" ::: "memory");
    __builtin_amdgcn_s_barrier();

    // A-fragment LDS byte offsets (row-major [128][128B], XOR-swizzled)
    uint32_t aoff0[4], aoff1[4];
    #pragma unroll
    for (int rt = 0; rt < 4; ++rt) {
        uint32_t arow = (uint32_t)(rowhalf * 64 + rt * 16 + lrow);
        uint32_t sw = (arow & 7u) << 4;
        aoff0[rt] = (arow * 128 + lk * 32) ^ sw;
        aoff1[rt] = (arow * 128 + lk * 32 + 16) ^ sw;
    }
    uint32_t boff[4];
    #pragma unroll
    for (int ct = 0; ct < 4; ++ct) {
        uint32_t n = (uint32_t)(colhalf * 64 + ct * 16 + lrow);
        boff[ct] = (n * 128 + lk * 16) ^ ((n & 7u) << 4);
    }

    f32x4 pe0[4], pe1[4];
    #pragma unroll
    for (int rt = 0; rt < 4; ++rt) {
        pe0[rt] = (f32x4){0.f, 0.f, 0.f, 0.f};
        pe1[rt] = (f32x4){0.f, 0.f, 0.f, 0.f};
    }

    for (int s = 0; s < NSTEPS; ++s) {
        int pb = (s + 3) & 3;
        stage_B(s + 3, pb);
        stage_A(s + 3, pb);

        int cur = s & 3;
        const char* ab = &As[cur][0];
        const char* bb = &Bs[cur][0];

        f32x4 a0[4], a1[4];
        bf16x8 ah[4], al[4];
        #pragma unroll
        for (int rt = 0; rt < 4; ++rt) {
            a0[rt] = *(const f32x4*)(ab + aoff0[rt]);
            a1[rt] = *(const f32x4*)(ab + aoff1[rt]);
            #pragma unroll
            for (int j = 0; j < 4; ++j) {
                float x = a0[rt][j];
                __bf16 h = (__bf16)x;
                ah[rt][j] = h;
                al[rt][j] = (__bf16)(x - (float)h);
                float y = a1[rt][j];
                __bf16 h2 = (__bf16)y;
                ah[rt][4 + j] = h2;
                al[rt][4 + j] = (__bf16)(y - (float)h2);
            }
        }

        bf16x8 bh[4], bl[4];
        #pragma unroll
        for (int ct = 0; ct < 4; ++ct) {
            bh[ct] = *(const bf16x8*)(bb + boff[ct]);
            bl[ct] = *(const bf16x8*)(bb + (boff[ct] ^ 64u));
        }

        // 3 passes x 4 ct x 4 rt; consecutive MFMAs hit different acc
        #pragma unroll
        for (int ct = 0; ct < 4; ++ct)
            #pragma unroll
            for (int rt = 0; rt < 4; ++rt)
                acc[rt][ct] = __builtin_amdgcn_mfma_f32_16x16x32_bf16(
                    ah[rt], bh[ct], acc[rt][ct], 0, 0, 0);
        #pragma unroll
        for (int ct = 0; ct < 4; ++ct)
            #pragma unroll
            for (int rt = 0; rt < 4; ++rt)
                acc[rt][ct] = __builtin_amdgcn_mfma_f32_16x16x32_bf16(
                    al[rt], bh[ct], acc[rt][ct], 0, 0, 0);
        #pragma unroll
        for (int ct = 0; ct < 4; ++ct)
            #pragma unroll
            for (int rt = 0; rt < 4; ++rt)
                acc[rt][ct] = __builtin_amdgcn_mfma_f32_16x16x32_bf16(
                    ah[rt], bl[ct], acc[rt][ct], 0, 0, 0);

        // ---- fused colsum (col-half-0 waves only; rows covered by rowhalf)
        if (colhalf == 0) {
            if ((s & 1) == 0) {
                #pragma unroll
                for (int rt = 0; rt < 4; ++rt) { pe0[rt] = a0[rt]; pe1[rt] = a1[rt]; }
            } else {
                float p[8];
                #pragma unroll
                for (int j = 0; j < 4; ++j) {
                    p[j]     = pe0[0][j] * a0[0][j];
                    p[4 + j] = pe1[0][j] * a1[0][j];
                    #pragma unroll
                    for (int rt = 1; rt < 4; ++rt) {
                        p[j]     += pe0[rt][j] * a0[rt][j];
                        p[4 + j] += pe1[rt][j] * a1[rt][j];
                    }
                }
                #pragma unroll
                for (int j = 0; j < 8; ++j) {
                    p[j] = dpp_ror_add<0x121>(p[j]);   // row_ror:1
                    p[j] = dpp_ror_add<0x122>(p[j]);   // row_ror:2
                    p[j] = dpp_ror_add<0x124>(p[j]);   // row_ror:4
                    p[j] = dpp_ror_add<0x128>(p[j]);   // row_ror:8
                }
                if (lrow == 0) {
                    int cb = (s >> 1) * 32 + lk * 8;
                    #pragma unroll
                    for (int j = 0; j < 8; ++j)
                        atomicAdd(&cs[cb + j], p[j]);
                }
            }
        }

        asm volatile("s_waitcnt vmcnt(16)" ::: "memory");
        __builtin_amdgcn_s_barrier();
    }

    // ---- store pre-activation ff (D frag: col=lane&15, row=(lane>>4)*4+v)
    #pragma unroll
    for (int rt = 0; rt < 4; ++rt)
        #pragma unroll
        for (int ct = 0; ct < 4; ++ct) {
            int colbase = colhalf * 64 + ct * 16 + lrow;
            #pragma unroll
            for (int v = 0; v < 4; ++v) {
                long row = m0 + rowhalf * 64 + rt * 16 + lk * 4 + v;
                ff[row * KOUT + colbase] = acc[rt][ct][v];
            }
        }

    __syncthreads();
    for (int i = tid; i < 1024; i += 256) atomicAdd(&colsum[i], cs[i]);
}

// ---------------- epilogue: out = tanh(ff + dvec), in place -------------------
__global__ __launch_bounds__(256) void epilogue_kernel(
    float* __restrict__ io, const float* __restrict__ dvec) {
    __shared__ float dv[KOUT];
    if (threadIdx.x < KOUT) dv[threadIdx.x] = dvec[threadIdx.x];
    __syncthreads();
    int t = blockIdx.x * 256 + threadIdx.x;        // 0..524287
    float4* io4 = (float4*)io;
    #pragma unroll
    for (int h = 0; h < 2; ++h) {
        int i = t + h * 524288;
        float4 v = io4[i];
        int c = (i & 31) * 4;
        v.x = tanhf(v.x + dv[c + 0]);
        v.y = tanhf(v.y + dv[c + 1]);
        v.z = tanhf(v.z + dv[c + 2]);
        v.w = tanhf(v.w + dv[c + 3]);
        io4[i] = v;
    }
}

extern "C" void kernel_launch(void* const* d_in, const int* in_sizes, int n_in,
                              void* d_out, int out_size, void* d_ws, size_t ws_size,
                              hipStream_t stream) {
    const float* e1 = (const float*)d_in[0];
    const float* e2 = (const float*)d_in[1];
    const float* W  = (const float*)d_in[2];
    const float* V  = (const float*)d_in[3];
    const float* b  = (const float*)d_in[4];
    float* out = (float*)d_out;

    int B = in_sizes[0] / D;               // 32768

    float* colsum = (float*)d_ws;                    // [1024]
    float* dvec   = colsum + D;                      // [128]
    char*  Vstage = (char*)d_ws + 8192;              // 64 x 16KB = 1 MB

    hipMemsetAsync(colsum, 0, D * sizeof(float), stream);

    vconv_kernel<<<(2 * D * KOUT) / 256, 256, 0, stream>>>(V, Vstage);

    // fused GEMM writes pre-activation ff into d_out and accumulates colsum
    mfma_gemm_fused<<<B / BM, 256, 0, stream>>>(e1, e2, Vstage, out, colsum);
    diag_kernel<<<KOUT, 256, 0, stream>>>(W, b, colsum, dvec,
                                          1.0f / ((float)D * (float)B));
    epilogue_kernel<<<(B * KOUT) / (256 * 8), 256, 0, stream>>>(out, dvec);
}

// Round 8
// 131.308 us; speedup vs baseline: 1.1648x; 1.1648x over previous
//
#include <hip/hip_runtime.h>
#include <stdint.h>

#define D 1024
#define KOUT 128
#define BM 64
#define NSTEPS 64

typedef __attribute__((ext_vector_type(8))) __bf16 bf16x8;
typedef __attribute__((ext_vector_type(4))) float f32x4;

// DPP row_ror add: v += rotate_within_16(v, N). Rows of 16 consecutive lanes.
template <int CTRL>
__device__ __forceinline__ float dpp_ror_add(float v) {
    int t = __builtin_amdgcn_update_dpp(
        0, __builtin_bit_cast(int, v), CTRL, 0xf, 0xf, true);
    return v + __builtin_bit_cast(float, t);
}

// ---------------- diag: dvec[i] = b[i] + (1/(d*B)) * sum_j W[i,j]*colsum[j] ----
__global__ __launch_bounds__(256) void diag_kernel(
    const float* __restrict__ W, const float* __restrict__ bias,
    const float* __restrict__ colsum, float* __restrict__ dvec, float inv_scale) {
    int i = blockIdx.x;
    int tid = threadIdx.x;
    float s = 0.f;
    for (int j = tid; j < D; j += 256) s += W[i * D + j] * colsum[j];
    #pragma unroll
    for (int off = 32; off > 0; off >>= 1) s += __shfl_down(s, off, 64);
    __shared__ float wsum[4];
    if ((tid & 63) == 0) wsum[tid >> 6] = s;
    __syncthreads();
    if (tid == 0)
        dvec[i] = bias[i] + (wsum[0] + wsum[1] + wsum[2] + wsum[3]) * inv_scale;
}

// ---------------- vconv: staging-ready, pre-swizzled hi/lo split of V ----------
__global__ __launch_bounds__(256) void vconv_kernel(
    const float* __restrict__ V, char* __restrict__ Vstage) {
    int idx = blockIdx.x * 256 + threadIdx.x;   // over 2048*128 elements of V[k][n]
    int k = idx >> 7;
    int n = idx & 127;
    float x = V[idx];
    __bf16 h = (__bf16)x;
    __bf16 l = (__bf16)(x - (float)h);
    int kstep = k >> 5;
    int kk = k & 31;
    uint32_t sw = ((uint32_t)(n & 7)) << 4;
    uint32_t oh = (uint32_t)(n * 128 + kk * 2);
    char* base = Vstage + (size_t)kstep * 16384;
    *(__bf16*)(base + (oh ^ sw)) = h;
    *(__bf16*)(base + ((oh + 64) ^ sw)) = l;
}

// ---------------- fused GEMM + colsum --------------------------------------
// Round-4 structure (depth-1 prefetch, one __syncthreads per step, 2 blocks/CU)
// with a 2x2 wave grid: wave = 32 rows x 64 cols (rt=2, ct=4) -> per wave-step
// 12 ds_read_b128 for 24 MFMAs (was 18 for 24). LDS 52 KB -> 2 blocks/CU.
// K-step order: s even -> e1 cols [t*32..), s odd -> e2 same cols (t=s>>1);
// fused colsum on colhalf==0 waves, DPP row_ror tree, LDS atomics.
__global__ __launch_bounds__(256) void mfma_gemm_fused(
    const float* __restrict__ e1, const float* __restrict__ e2,
    const char* __restrict__ Vstage, float* __restrict__ ff,
    float* __restrict__ colsum) {
    __shared__ char As[2][8192];
    __shared__ char Bs[2][16384];
    __shared__ float cs[1024];

    int tid  = threadIdx.x;
    int wave = tid >> 6;
    int lane = tid & 63;
    int lrow = lane & 15;
    int lk   = lane >> 4;                  // 0..3
    int rowhalf = wave & 1;
    int colhalf = wave >> 1;
    long m0  = (long)blockIdx.x * BM;

    for (int i = tid; i < 1024; i += 256) cs[i] = 0.f;

    f32x4 acc[2][4];
    #pragma unroll
    for (int rt = 0; rt < 2; ++rt)
        #pragma unroll
        for (int ct = 0; ct < 4; ++ct) acc[rt][ct] = (f32x4){0.f, 0.f, 0.f, 0.f};

    auto stage = [&](int s, int buf) {
        int ss = s & 63;
        const float* src = (ss & 1) ? e2 : e1;
        int kcb = (ss >> 1) << 7;          // byte col offset = t*32 floats
        #pragma unroll
        for (int r = 0; r < 2; ++r) {
            uint32_t slot = (uint32_t)(r * 4096 + tid * 16);
            uint32_t row  = slot >> 7;     // 0..63
            uint32_t o    = slot ^ ((row & 7u) << 4);
            const char* g = (const char*)src + (((long)(m0 + row)) << 12)
                            + kcb + (o & 127u);
            char* l = &As[buf][r * 4096 + wave * 1024];
            __builtin_amdgcn_global_load_lds(
                (const __attribute__((address_space(1))) uint32_t*)g,
                (__attribute__((address_space(3))) uint32_t*)l, 16, 0, 0);
        }
        int bt = ((ss & 1) << 5) + (ss >> 1);
        const char* gb = Vstage + (size_t)bt * 16384;
        #pragma unroll
        for (int r = 0; r < 4; ++r) {
            const char* g = gb + r * 4096 + tid * 16;
            char* l = &Bs[buf][r * 4096 + wave * 1024];
            __builtin_amdgcn_global_load_lds(
                (const __attribute__((address_space(1))) uint32_t*)g,
                (__attribute__((address_space(3))) uint32_t*)l, 16, 0, 0);
        }
    };

    stage(0, 0);
    __syncthreads();

    // A-fragment LDS byte offsets ([64 rows][128B], XOR-swizzled)
    uint32_t aoff0[2], aoff1[2];
    #pragma unroll
    for (int rt = 0; rt < 2; ++rt) {
        uint32_t arow = (uint32_t)(rowhalf * 32 + rt * 16 + lrow);
        uint32_t sw = (arow & 7u) << 4;
        aoff0[rt] = (arow * 128 + lk * 32) ^ sw;
        aoff1[rt] = (arow * 128 + lk * 32 + 16) ^ sw;
    }
    // B-fragment offsets ([128 n][hi 64B | lo 64B], XOR-swizzled)
    uint32_t boff[4];
    #pragma unroll
    for (int ct = 0; ct < 4; ++ct) {
        uint32_t n = (uint32_t)(colhalf * 64 + ct * 16 + lrow);
        boff[ct] = (n * 128 + lk * 16) ^ ((n & 7u) << 4);
    }

    f32x4 pe0[2], pe1[2];
    #pragma unroll
    for (int rt = 0; rt < 2; ++rt) {
        pe0[rt] = (f32x4){0.f, 0.f, 0.f, 0.f};
        pe1[rt] = (f32x4){0.f, 0.f, 0.f, 0.f};
    }

    for (int s = 0; s < NSTEPS; ++s) {
        int cur = s & 1;
        if (s + 1 < NSTEPS) stage(s + 1, cur ^ 1);

        const char* ab = &As[cur][0];
        const char* bb = &Bs[cur][0];

        f32x4 a0[2], a1[2];
        bf16x8 ah[2], al[2];
        #pragma unroll
        for (int rt = 0; rt < 2; ++rt) {
            a0[rt] = *(const f32x4*)(ab + aoff0[rt]);
            a1[rt] = *(const f32x4*)(ab + aoff1[rt]);
            #pragma unroll
            for (int j = 0; j < 4; ++j) {
                float x = a0[rt][j];
                __bf16 h = (__bf16)x;
                ah[rt][j] = h;
                al[rt][j] = (__bf16)(x - (float)h);
                float y = a1[rt][j];
                __bf16 h2 = (__bf16)y;
                ah[rt][4 + j] = h2;
                al[rt][4 + j] = (__bf16)(y - (float)h2);
            }
        }

        bf16x8 bh[4], bl[4];
        #pragma unroll
        for (int ct = 0; ct < 4; ++ct) {
            bh[ct] = *(const bf16x8*)(bb + boff[ct]);
            bl[ct] = *(const bf16x8*)(bb + (boff[ct] ^ 64u));
        }

        // 3 passes x 4 ct x 2 rt; consecutive MFMAs hit different acc
        #pragma unroll
        for (int ct = 0; ct < 4; ++ct)
            #pragma unroll
            for (int rt = 0; rt < 2; ++rt)
                acc[rt][ct] = __builtin_amdgcn_mfma_f32_16x16x32_bf16(
                    ah[rt], bh[ct], acc[rt][ct], 0, 0, 0);
        #pragma unroll
        for (int ct = 0; ct < 4; ++ct)
            #pragma unroll
            for (int rt = 0; rt < 2; ++rt)
                acc[rt][ct] = __builtin_amdgcn_mfma_f32_16x16x32_bf16(
                    al[rt], bh[ct], acc[rt][ct], 0, 0, 0);
        #pragma unroll
        for (int ct = 0; ct < 4; ++ct)
            #pragma unroll
            for (int rt = 0; rt < 2; ++rt)
                acc[rt][ct] = __builtin_amdgcn_mfma_f32_16x16x32_bf16(
                    ah[rt], bl[ct], acc[rt][ct], 0, 0, 0);

        // ---- fused colsum (colhalf==0 waves; rows covered via rowhalf)
        if (colhalf == 0) {
            if ((s & 1) == 0) {
                #pragma unroll
                for (int rt = 0; rt < 2; ++rt) { pe0[rt] = a0[rt]; pe1[rt] = a1[rt]; }
            } else {
                float p[8];
                #pragma unroll
                for (int j = 0; j < 4; ++j) {
                    p[j]     = pe0[0][j] * a0[0][j] + pe0[1][j] * a0[1][j];
                    p[4 + j] = pe1[0][j] * a1[0][j] + pe1[1][j] * a1[1][j];
                }
                #pragma unroll
                for (int j = 0; j < 8; ++j) {
                    p[j] = dpp_ror_add<0x121>(p[j]);   // row_ror:1
                    p[j] = dpp_ror_add<0x122>(p[j]);   // row_ror:2
                    p[j] = dpp_ror_add<0x124>(p[j]);   // row_ror:4
                    p[j] = dpp_ror_add<0x128>(p[j]);   // row_ror:8
                }
                if (lrow == 0) {
                    int cb = (s >> 1) * 32 + lk * 8;
                    #pragma unroll
                    for (int j = 0; j < 8; ++j)
                        atomicAdd(&cs[cb + j], p[j]);
                }
            }
        }

        __syncthreads();
    }

    // ---- store pre-activation ff (D frag: col=lane&15, row=(lane>>4)*4+v)
    #pragma unroll
    for (int rt = 0; rt < 2; ++rt)
        #pragma unroll
        for (int ct = 0; ct < 4; ++ct) {
            int colbase = colhalf * 64 + ct * 16 + lrow;
            #pragma unroll
            for (int v = 0; v < 4; ++v) {
                long row = m0 + rowhalf * 32 + rt * 16 + lk * 4 + v;
                ff[row * KOUT + colbase] = acc[rt][ct][v];
            }
        }

    __syncthreads();
    for (int i = tid; i < 1024; i += 256) atomicAdd(&colsum[i], cs[i]);
}

// ---------------- epilogue: out = tanh(ff + dvec), in place -------------------
__global__ __launch_bounds__(256) void epilogue_kernel(
    float* __restrict__ io, const float* __restrict__ dvec) {
    __shared__ float dv[KOUT];
    if (threadIdx.x < KOUT) dv[threadIdx.x] = dvec[threadIdx.x];
    __syncthreads();
    int t = blockIdx.x * 256 + threadIdx.x;        // 0..524287
    float4* io4 = (float4*)io;
    #pragma unroll
    for (int h = 0; h < 2; ++h) {
        int i = t + h * 524288;
        float4 v = io4[i];
        int c = (i & 31) * 4;
        v.x = tanhf(v.x + dv[c + 0]);
        v.y = tanhf(v.y + dv[c + 1]);
        v.z = tanhf(v.z + dv[c + 2]);
        v.w = tanhf(v.w + dv[c + 3]);
        io4[i] = v;
    }
}

extern "C" void kernel_launch(void* const* d_in, const int* in_sizes, int n_in,
                              void* d_out, int out_size, void* d_ws, size_t ws_size,
                              hipStream_t stream) {
    const float* e1 = (const float*)d_in[0];
    const float* e2 = (const float*)d_in[1];
    const float* W  = (const float*)d_in[2];
    const float* V  = (const float*)d_in[3];
    const float* b  = (const float*)d_in[4];
    float* out = (float*)d_out;

    int B = in_sizes[0] / D;               // 32768

    float* colsum = (float*)d_ws;                    // [1024]
    float* dvec   = colsum + D;                      // [128]
    char*  Vstage = (char*)d_ws + 8192;              // 64 x 16KB = 1 MB

    hipMemsetAsync(colsum, 0, D * sizeof(float), stream);

    vconv_kernel<<<(2 * D * KOUT) / 256, 256, 0, stream>>>(V, Vstage);

    // fused GEMM writes pre-activation ff into d_out and accumulates colsum
    mfma_gemm_fused<<<B / BM, 256, 0, stream>>>(e1, e2, Vstage, out, colsum);
    diag_kernel<<<KOUT, 256, 0, stream>>>(W, b, colsum, dvec,
                                          1.0f / ((float)D * (float)B));
    epilogue_kernel<<<(B * KOUT) / (256 * 8), 256, 0, stream>>>(out, dvec);
}